// Round 3
// baseline (1160.265 us; speedup 1.0000x reference)
//
#include <hip/hip_runtime.h>

typedef __bf16 bf16_t;
typedef __bf16 bf16x8 __attribute__((ext_vector_type(8)));
typedef __bf16 bf16x4 __attribute__((ext_vector_type(4)));
typedef float  f32x4  __attribute__((ext_vector_type(4)));
typedef int    i32x4  __attribute__((ext_vector_type(4)));

#define TT 64
#define PL 136   // padded row stride (elems) for [t][128] bf16 tiles
#define PX 264   // padded row stride (elems) for [t][256] bf16 tiles

__device__ __forceinline__ f32x4 mfma16(bf16x8 a, bf16x8 b, f32x4 c) {
    return __builtin_amdgcn_mfma_f32_16x16x32_bf16(a, b, c, 0, 0, 0);
}

// ---------------- weight conversion to MFMA fragment order ----------------
// frag index: ((mt*KB + kb)*64 + lane)*8 + j  <->  m = mt*16 + (lane&15),
// k = kb*32 + (lane>>4)*8 + j.  src is row-major [M][K].
__global__ void conv_batch(const float* __restrict__ src, bf16_t* __restrict__ dst,
                           int M, int K, int cnt) {
    int idx = blockIdx.x * 256 + threadIdx.x;
    int MK = M * K;
    if (idx >= MK * cnt) return;
    int lay = idx / MK;
    int r = idx - lay * MK;
    int j = r & 7, lane = (r >> 3) & 63, rest = r >> 9;
    int KB = K >> 5;
    int kb = rest % KB, mt = rest / KB;
    int m = mt * 16 + (lane & 15);
    int k = kb * 32 + ((lane >> 4) << 3) + j;
    dst[idx] = (bf16_t)src[(size_t)lay * MK + m * K + k];
}

// dil_w [30][256][128][2] -> per-layer A[256][256]: k<128 tap0(delayed), k>=128 tap1
__global__ void conv_dil(const float* __restrict__ dw, bf16_t* __restrict__ dst) {
    int idx = blockIdx.x * 256 + threadIdx.x;   // 30*65536 total
    int lay = idx >> 16, r = idx & 65535;
    int j = r & 7, lane = (r >> 3) & 63, rest = r >> 9;
    int kb = rest & 7, mt = rest >> 3;
    int m = mt * 16 + (lane & 15);
    int k = kb * 32 + ((lane >> 4) << 3) + j;
    float v = (k < 128) ? dw[(((size_t)lay * 256 + m) * 128 + k) * 2]
                        : dw[(((size_t)lay * 256 + m) * 128 + (k - 128)) * 2 + 1];
    dst[idx] = (bf16_t)v;
}

// ---------------- conditioning precompute ----------------
__global__ void cond_kernel(const float* __restrict__ cond_w,
                            const float* __restrict__ end2_w,
                            const float* __restrict__ end2_b,
                            const float* __restrict__ en,
                            float* __restrict__ cond_all,
                            float* __restrict__ cond2) {
    __shared__ f32x4 en_s[1024];  // en[n]: [256 c][16 e] as 4 f32x4 per c
    int bi = blockIdx.x;
    int i = bi >> 2, n = bi & 3, o = threadIdx.x;
    const f32x4* ep = (const f32x4*)(en + (size_t)n * 4096);
    for (int idx = threadIdx.x; idx < 1024; idx += 256) en_s[idx] = ep[idx];
    __syncthreads();
    const float* W = (i < 30) ? cond_w + ((size_t)i * 256 + o) * 256
                              : end2_w + (size_t)o * 256;
    f32x4 a0 = {0.f,0.f,0.f,0.f}, a1 = a0, a2 = a0, a3 = a0;
    for (int c = 0; c < 256; c += 4) {
        f32x4 wv = *(const f32x4*)(W + c);
        #pragma unroll
        for (int cc = 0; cc < 4; ++cc) {
            float wf = wv[cc];
            a0 += wf * en_s[(c + cc) * 4 + 0];
            a1 += wf * en_s[(c + cc) * 4 + 1];
            a2 += wf * en_s[(c + cc) * 4 + 2];
            a3 += wf * en_s[(c + cc) * 4 + 3];
        }
    }
    float bias = (i < 30) ? 0.f : end2_b[o];
    float* dst = (i < 30) ? cond_all + (((size_t)i * 4 + n) * 256 + o) * 16
                          : cond2 + ((size_t)n * 256 + o) * 16;
    f32x4* d4 = (f32x4*)dst;
    d4[0] = a0 + bias; d4[1] = a1 + bias; d4[2] = a2 + bias; d4[3] = a3 + bias;
}

// ---------------- start: l0 = start1@x (t>=64); s0 = start2@l0 (t>=4096) -------
__global__ __launch_bounds__(512) void start_kernel(
    const float* __restrict__ x, bf16_t* __restrict__ l_out,
    float* __restrict__ s, const bf16_t* __restrict__ A1,
    const bf16_t* __restrict__ A2) {
    __shared__ __align__(16) bf16_t xt[TT * PX];
    __shared__ __align__(16) bf16_t l0[TT * PL];
    int tid = threadIdx.x;
    int n = blockIdx.y, t0 = 64 + blockIdx.x * TT;
    int lane = tid & 63, w = tid >> 6, i16 = lane & 15, q = lane >> 4;

    {   // stage x tile transposed -> [t][c] bf16
        int t = tid & 63;
        for (int c = tid >> 6; c < 256; c += 8)
            xt[t * PX + c] = (bf16_t)x[((size_t)n * 256 + c) * 8192 + t0 + t];
    }
    __syncthreads();

    // GEMM l0: M=128 (wave w -> mtile w), K=256
    f32x4 z = {0.f,0.f,0.f,0.f};
    f32x4 acc[4] = {z, z, z, z};
    #pragma unroll
    for (int kb = 0; kb < 8; ++kb) {
        int koff = kb * 32 + q * 8;
        bf16x8 bf[4];
        #pragma unroll
        for (int nt = 0; nt < 4; ++nt)
            bf[nt] = *(const bf16x8*)(xt + (nt * 16 + i16) * PX + koff);
        bf16x8 af = *(const bf16x8*)(A1 + (((size_t)w * 8 + kb) * 64 + lane) * 8);
        #pragma unroll
        for (int nt = 0; nt < 4; ++nt) acc[nt] = mfma16(af, bf[nt], acc[nt]);
    }
    #pragma unroll
    for (int nt = 0; nt < 4; ++nt)
        #pragma unroll
        for (int j = 0; j < 4; ++j)
            l0[(nt * 16 + i16) * PL + w * 16 + q * 4 + j] = (bf16_t)acc[nt][j];
    __syncthreads();

    {   // copy l0 -> global [N][L][128]
        int r = tid >> 4, col = (tid & 15) * 8;
        #pragma unroll
        for (int p = 0; p < 2; ++p) {
            int rr = r + p * 32;
            *(i32x4*)(l_out + ((size_t)n * 8192 + t0 + rr) * 128 + col) =
                *(const i32x4*)(l0 + rr * PL + col);
        }
    }

    if (t0 >= 4096) {  // s0: M=256, K=128
        f32x4 a2[2][4] = {{z,z,z,z},{z,z,z,z}};
        #pragma unroll
        for (int kb = 0; kb < 4; ++kb) {
            int koff = kb * 32 + q * 8;
            bf16x8 bf[4];
            #pragma unroll
            for (int nt = 0; nt < 4; ++nt)
                bf[nt] = *(const bf16x8*)(l0 + (nt * 16 + i16) * PL + koff);
            #pragma unroll
            for (int mt2 = 0; mt2 < 2; ++mt2) {
                bf16x8 af = *(const bf16x8*)(A2 + ((((size_t)2 * w + mt2) * 4 + kb) * 64 + lane) * 8);
                #pragma unroll
                for (int nt = 0; nt < 4; ++nt) a2[mt2][nt] = mfma16(af, bf[nt], a2[mt2][nt]);
            }
        }
        float* sp = s + (size_t)n * 256 * 4096 + (t0 - 4096);
        #pragma unroll
        for (int mt2 = 0; mt2 < 2; ++mt2)
            #pragma unroll
            for (int nt = 0; nt < 4; ++nt)
                #pragma unroll
                for (int j = 0; j < 4; ++j) {
                    int o = (2 * w + mt2) * 16 + q * 4 + j;
                    sp[(size_t)o * 4096 + nt * 16 + i16] = a2[mt2][nt][j];
                }
    }
}

// ---------------- fused WaveNet layer (wave owns 16 positions, gate in-register)
__global__ __launch_bounds__(512, 4) void layer_kernel(
    const bf16_t* __restrict__ l_in, bf16_t* __restrict__ l_out,
    float* __restrict__ s,
    const bf16_t* __restrict__ Ad, const bf16_t* __restrict__ Ar,
    const bf16_t* __restrict__ Ak, const float* __restrict__ cond,
    int dil, int t_base, int do_res) {
    __shared__ __align__(16) bf16_t l_cur[TT * PL];
    __shared__ __align__(16) bf16_t l_del[TT * PL];   // after GEMM1: reused for bf16 sum
    __shared__ __align__(16) bf16_t g_lds[TT * PL];

    int tid = threadIdx.x;
    int n = blockIdx.y, t0 = t_base + blockIdx.x * TT;
    int lane = tid & 63, w = tid >> 6, i16 = lane & 15, q = lane >> 4;
    int nt = w & 3, mg = w >> 2;     // wave owns ntile nt, m-group mg

    {   // stage l_cur, l_del (delayed by dil, zero-pad)
        int r = tid >> 4, col = (tid & 15) * 8;
        size_t base = (size_t)n * 8192;
        #pragma unroll
        for (int p = 0; p < 2; ++p) {
            int rr = r + p * 32;
            *(i32x4*)(l_cur + rr * PL + col) =
                *(const i32x4*)(l_in + (base + t0 + rr) * 128 + col);
            int gp = t0 - dil + rr;
            i32x4 v = {0, 0, 0, 0};
            if (gp >= 0) v = *(const i32x4*)(l_in + (base + gp) * 128 + col);
            *(i32x4*)(l_del + rr * PL + col) = v;
        }
    }
    __syncthreads();

    // GEMM1: d = [W0 W1] @ [l_del; l_cur].  Wave computes mtiles
    // {mg*4+p} (sigmoid half) and {mg*4+p+8} (tanh half) for its ntile.
    f32x4 z = {0.f,0.f,0.f,0.f};
    f32x4 accs[4] = {z,z,z,z}, acct[4] = {z,z,z,z};
    const bf16x8* AdF = (const bf16x8*)Ad;
    int trow = (nt * 16 + i16) * PL;
    #pragma unroll
    for (int kb = 0; kb < 8; ++kb) {
        const bf16_t* bsrc = (kb < 4) ? l_del : l_cur;
        bf16x8 bf = *(const bf16x8*)(bsrc + trow + (kb & 3) * 32 + q * 8);
        #pragma unroll
        for (int p = 0; p < 4; ++p) {
            int mts = mg * 4 + p;
            bf16x8 a_s = AdF[((size_t)mts * 8 + kb) * 64 + lane];
            bf16x8 a_t = AdF[((size_t)(mts + 8) * 8 + kb) * 64 + lane];
            accs[p] = mfma16(a_s, bf, accs[p]);
            acct[p] = mfma16(a_t, bf, acct[p]);
        }
    }

    // gate fully in-register: g[c] = sigmoid(d[c]+cv) * tanh(d[c+128]+cv')
    {
        const float* cn = cond + (size_t)n * 4096;
        #pragma unroll
        for (int p = 0; p < 4; ++p) {
            int c_base = (mg * 4 + p) * 16 + q * 4;
            bf16x4 g4;
            #pragma unroll
            for (int j = 0; j < 4; ++j) {
                float vlo = accs[p][j] + cn[(c_base + j) * 16 + i16];
                float vhi = acct[p][j] + cn[(c_base + j + 128) * 16 + i16];
                float sg = 1.0f / (1.0f + __expf(-vlo));
                float th = 1.0f - 2.0f / (1.0f + __expf(2.0f * vhi));
                g4[j] = (bf16_t)(sg * th);
            }
            *(bf16x4*)(g_lds + trow + c_base) = g4;
        }
    }
    __syncthreads();   // also: all GEMM1 reads of l_del are done from here on

    // GEMM2 (res, this wave: mtiles mg*4+p) + GEMM3 (skip, mtiles mg*8+p), K=128
    int do_skip = (t0 >= 4096);
    f32x4 acc2[4] = {z,z,z,z};
    f32x4 acc3[8] = {z,z,z,z,z,z,z,z};
    const bf16x8* ArF = (const bf16x8*)Ar;
    const bf16x8* AkF = (const bf16x8*)Ak;
    #pragma unroll
    for (int kb = 0; kb < 4; ++kb) {
        bf16x8 bf = *(const bf16x8*)(g_lds + trow + kb * 32 + q * 8);
        if (do_res) {
            #pragma unroll
            for (int p = 0; p < 4; ++p) {
                bf16x8 ar = ArF[((size_t)(mg * 4 + p) * 4 + kb) * 64 + lane];
                acc2[p] = mfma16(ar, bf, acc2[p]);
            }
        }
        if (do_skip) {
            #pragma unroll
            for (int p = 0; p < 8; ++p) {
                bf16x8 ak = AkF[((size_t)(mg * 8 + p) * 4 + kb) * 64 + lane];
                acc3[p] = mfma16(ak, bf, acc3[p]);
            }
        }
    }

    if (do_skip) {   // accumulate into s (only t >= 4096 contributes to output)
        float* sp = s + (size_t)n * 256 * 4096 + (t0 - 4096) + nt * 16 + i16;
        #pragma unroll
        for (int p = 0; p < 8; ++p)
            #pragma unroll
            for (int j = 0; j < 4; ++j) {
                int o = (mg * 8 + p) * 16 + q * 4 + j;
                sp[(size_t)o * 4096] += acc3[p][j];
            }
    }

    if (do_res) {
        // sum = f32(l_cur) + res, single rounding to bf16, into l_del [t][PL]
        #pragma unroll
        for (int p = 0; p < 4; ++p) {
            int c_base = (mg * 4 + p) * 16 + q * 4;
            bf16x4 lv = *(const bf16x4*)(l_cur + trow + c_base);
            bf16x4 o4;
            #pragma unroll
            for (int j = 0; j < 4; ++j)
                o4[j] = (bf16_t)((float)lv[j] + acc2[p][j]);
            *(bf16x4*)(l_del + trow + c_base) = o4;
        }
        __syncthreads();
        // coalesced copy l_del -> l_out
        int t = tid >> 3, c0 = (tid & 7) * 16;
        bf16_t* dst = l_out + ((size_t)n * 8192 + t0 + t) * 128 + c0;
        *(i32x4*)dst = *(const i32x4*)(l_del + t * PL + c0);
        *(i32x4*)(dst + 8) = *(const i32x4*)(l_del + t * PL + c0 + 8);
    }
}

// ---------------- end: out = relu(end1@relu(s) + b1 + cond2_tiled) ----------------
__global__ __launch_bounds__(512) void end_kernel(
    const float* __restrict__ s, float* __restrict__ out,
    const bf16_t* __restrict__ Ae, const float* __restrict__ cond2,
    const float* __restrict__ b1) {
    __shared__ __align__(16) bf16_t st[TT * PX];
    __shared__ float c2[4096];
    __shared__ float b1s[256];
    int tid = threadIdx.x;
    int n = blockIdx.y, t0 = blockIdx.x * TT;
    int lane = tid & 63, w = tid >> 6, i16 = lane & 15, q = lane >> 4;

    {
        int t = tid & 63;
        for (int c = tid >> 6; c < 256; c += 8) {
            float v = s[((size_t)n * 256 + c) * 4096 + t0 + t];
            st[t * PX + c] = (bf16_t)fmaxf(v, 0.f);
        }
        const f32x4* cc = (const f32x4*)(cond2 + (size_t)n * 4096);
        for (int idx = tid; idx < 1024; idx += 512) ((f32x4*)c2)[idx] = cc[idx];
        if (tid < 64) ((f32x4*)b1s)[tid] = ((const f32x4*)b1)[tid];
    }
    __syncthreads();

    f32x4 z = {0.f,0.f,0.f,0.f};
    f32x4 acc[2][4] = {{z,z,z,z},{z,z,z,z}};
    #pragma unroll
    for (int kb = 0; kb < 8; ++kb) {
        int koff = kb * 32 + q * 8;
        bf16x8 bf[4];
        #pragma unroll
        for (int nt = 0; nt < 4; ++nt)
            bf[nt] = *(const bf16x8*)(st + (nt * 16 + i16) * PX + koff);
        #pragma unroll
        for (int mt2 = 0; mt2 < 2; ++mt2) {
            bf16x8 af = *(const bf16x8*)(Ae + ((((size_t)2 * w + mt2) * 8 + kb) * 64 + lane) * 8);
            #pragma unroll
            for (int nt = 0; nt < 4; ++nt) acc[mt2][nt] = mfma16(af, bf[nt], acc[mt2][nt]);
        }
    }
    #pragma unroll
    for (int mt2 = 0; mt2 < 2; ++mt2)
        #pragma unroll
        for (int j = 0; j < 4; ++j) {
            int o = (2 * w + mt2) * 16 + q * 4 + j;
            float bb = b1s[o] + c2[o * 16 + i16];
            #pragma unroll
            for (int nt = 0; nt < 4; ++nt) {
                float v = acc[mt2][nt][j] + bb;
                out[((size_t)n * 256 + o) * 4096 + t0 + nt * 16 + i16] = fmaxf(v, 0.f);
            }
        }
}

extern "C" void kernel_launch(void* const* d_in, const int* in_sizes, int n_in,
                              void* d_out, int out_size, void* d_ws, size_t ws_size,
                              hipStream_t stream) {
    const float* x   = (const float*)d_in[0];
    const float* en  = (const float*)d_in[1];
    const float* s1w = (const float*)d_in[2];
    const float* s2w = (const float*)d_in[3];
    const float* cw  = (const float*)d_in[4];
    const float* dw  = (const float*)d_in[5];
    const float* rw  = (const float*)d_in[6];
    const float* kw  = (const float*)d_in[7];
    const float* e1w = (const float*)d_in[8];
    const float* e1b = (const float*)d_in[9];
    const float* e2w = (const float*)d_in[10];
    const float* e2b = (const float*)d_in[11];
    float* out = (float*)d_out;

    char* p = (char*)d_ws;
    auto take = [&](size_t bytes) {
        char* r = p;
        p += (bytes + 255) & ~(size_t)255;
        return r;
    };
    bf16_t* A1   = (bf16_t*)take((size_t)128 * 256 * 2);
    bf16_t* A2   = (bf16_t*)take((size_t)256 * 128 * 2);
    bf16_t* Ae   = (bf16_t*)take((size_t)256 * 256 * 2);
    bf16_t* Adil = (bf16_t*)take((size_t)30 * 65536 * 2);
    bf16_t* Ares = (bf16_t*)take((size_t)30 * 16384 * 2);
    bf16_t* Askp = (bf16_t*)take((size_t)30 * 32768 * 2);
    float*  condA= (float*)take((size_t)30 * 16384 * 4);
    float*  cond2= (float*)take((size_t)16384 * 4);
    bf16_t* la   = (bf16_t*)take((size_t)4 * 8192 * 128 * 2);
    bf16_t* lb   = (bf16_t*)take((size_t)4 * 8192 * 128 * 2);
    float*  sbuf = (float*)take((size_t)4 * 256 * 4096 * 4);

    conv_batch<<<30 * 16384 / 256, 256, 0, stream>>>(rw, Ares, 128, 128, 30);
    conv_batch<<<30 * 32768 / 256, 256, 0, stream>>>(kw, Askp, 256, 128, 30);
    conv_batch<<<128 * 256 / 256, 256, 0, stream>>>(s1w, A1, 128, 256, 1);
    conv_batch<<<256 * 128 / 256, 256, 0, stream>>>(s2w, A2, 256, 128, 1);
    conv_batch<<<256 * 256 / 256, 256, 0, stream>>>(e1w, Ae, 256, 256, 1);
    conv_dil<<<30 * 65536 / 256, 256, 0, stream>>>(dw, Adil);
    cond_kernel<<<124, 256, 0, stream>>>(cw, e2w, e2b, en, condA, cond2);

    // causal trim: a[i] = first (tile-aligned) position layer i must compute
    int a[30];
    a[29] = 4096;
    for (int i = 28; i >= 0; --i) {
        int nx = a[i + 1] - (1 << ((i + 1) % 10));
        a[i] = nx < 4096 ? (nx & ~63) : 4096;
    }

    start_kernel<<<dim3(127, 4), 512, 0, stream>>>(x, la, sbuf, A1, A2);
    bf16_t* src = la;
    bf16_t* dst = lb;
    for (int i = 0; i < 30; ++i) {
        int ntiles = (8192 - a[i]) / 64;
        layer_kernel<<<dim3(ntiles, 4), 512, 0, stream>>>(src, dst, sbuf,
            Adil + (size_t)i * 65536, Ares + (size_t)i * 16384,
            Askp + (size_t)i * 32768, condA + (size_t)i * 16384,
            1 << (i % 10), a[i], i < 29 ? 1 : 0);
        bf16_t* t = src; src = dst; dst = t;
    }
    end_kernel<<<dim3(64, 4), 512, 0, stream>>>(sbuf, out, Ae, cond2, e1b);
}

// Round 4
// 736.594 us; speedup vs baseline: 1.5752x; 1.5752x over previous
//
#include <hip/hip_runtime.h>

typedef __bf16 bf16_t;
typedef __bf16 bf16x8 __attribute__((ext_vector_type(8)));
typedef __bf16 bf16x4 __attribute__((ext_vector_type(4)));
typedef float  f32x4  __attribute__((ext_vector_type(4)));
typedef int    i32x4  __attribute__((ext_vector_type(4)));

#define TT 64
#define PL 136   // padded row stride (elems) for [t][128] bf16 tiles
#define PX 264   // padded row stride (elems) for [t][256] bf16 tiles

__device__ __forceinline__ f32x4 mfma16(bf16x8 a, bf16x8 b, f32x4 c) {
    return __builtin_amdgcn_mfma_f32_16x16x32_bf16(a, b, c, 0, 0, 0);
}

// ---------------- weight conversion to MFMA fragment order ----------------
// frag index: ((mt*KB + kb)*64 + lane)*8 + j  <->  m = mt*16 + (lane&15),
// k = kb*32 + (lane>>4)*8 + j.  src is row-major [M][K].
__global__ void conv_batch(const float* __restrict__ src, bf16_t* __restrict__ dst,
                           int M, int K, int cnt) {
    int idx = blockIdx.x * 256 + threadIdx.x;
    int MK = M * K;
    if (idx >= MK * cnt) return;
    int lay = idx / MK;
    int r = idx - lay * MK;
    int j = r & 7, lane = (r >> 3) & 63, rest = r >> 9;
    int KB = K >> 5;
    int kb = rest % KB, mt = rest / KB;
    int m = mt * 16 + (lane & 15);
    int k = kb * 32 + ((lane >> 4) << 3) + j;
    dst[idx] = (bf16_t)src[(size_t)lay * MK + m * K + k];
}

// dil_w [30][256][128][2] -> per-layer A[256][256]: k<128 tap0(delayed), k>=128 tap1
__global__ void conv_dil(const float* __restrict__ dw, bf16_t* __restrict__ dst) {
    int idx = blockIdx.x * 256 + threadIdx.x;   // 30*65536 total
    int lay = idx >> 16, r = idx & 65535;
    int j = r & 7, lane = (r >> 3) & 63, rest = r >> 9;
    int kb = rest & 7, mt = rest >> 3;
    int m = mt * 16 + (lane & 15);
    int k = kb * 32 + ((lane >> 4) << 3) + j;
    float v = (k < 128) ? dw[(((size_t)lay * 256 + m) * 128 + k) * 2]
                        : dw[(((size_t)lay * 256 + m) * 128 + (k - 128)) * 2 + 1];
    dst[idx] = (bf16_t)v;
}

// ---------------- conditioning precompute ----------------
__global__ void cond_kernel(const float* __restrict__ cond_w,
                            const float* __restrict__ end2_w,
                            const float* __restrict__ end2_b,
                            const float* __restrict__ en,
                            float* __restrict__ cond_all,
                            float* __restrict__ cond2) {
    __shared__ f32x4 en_s[1024];  // en[n]: [256 c][16 e] as 4 f32x4 per c
    int bi = blockIdx.x;
    int i = bi >> 2, n = bi & 3, o = threadIdx.x;
    const f32x4* ep = (const f32x4*)(en + (size_t)n * 4096);
    for (int idx = threadIdx.x; idx < 1024; idx += 256) en_s[idx] = ep[idx];
    __syncthreads();
    const float* W = (i < 30) ? cond_w + ((size_t)i * 256 + o) * 256
                              : end2_w + (size_t)o * 256;
    f32x4 a0 = {0.f,0.f,0.f,0.f}, a1 = a0, a2 = a0, a3 = a0;
    for (int c = 0; c < 256; c += 4) {
        f32x4 wv = *(const f32x4*)(W + c);
        #pragma unroll
        for (int cc = 0; cc < 4; ++cc) {
            float wf = wv[cc];
            a0 += wf * en_s[(c + cc) * 4 + 0];
            a1 += wf * en_s[(c + cc) * 4 + 1];
            a2 += wf * en_s[(c + cc) * 4 + 2];
            a3 += wf * en_s[(c + cc) * 4 + 3];
        }
    }
    float bias = (i < 30) ? 0.f : end2_b[o];
    float* dst = (i < 30) ? cond_all + (((size_t)i * 4 + n) * 256 + o) * 16
                          : cond2 + ((size_t)n * 256 + o) * 16;
    f32x4* d4 = (f32x4*)dst;
    d4[0] = a0 + bias; d4[1] = a1 + bias; d4[2] = a2 + bias; d4[3] = a3 + bias;
}

// ---------------- start: l0 = start1@x (t>=64); s0 = start2@l0 (t>=4096) -------
__global__ __launch_bounds__(512) void start_kernel(
    const float* __restrict__ x, bf16_t* __restrict__ l_out,
    float* __restrict__ s, const bf16_t* __restrict__ A1,
    const bf16_t* __restrict__ A2) {
    __shared__ __align__(16) bf16_t xt[TT * PX];
    __shared__ __align__(16) bf16_t l0[TT * PL];
    int tid = threadIdx.x;
    int n = blockIdx.y, t0 = 64 + blockIdx.x * TT;
    int lane = tid & 63, w = tid >> 6, i16 = lane & 15, q = lane >> 4;

    {   // stage x tile transposed -> [t][c] bf16
        int t = tid & 63;
        for (int c = tid >> 6; c < 256; c += 8)
            xt[t * PX + c] = (bf16_t)x[((size_t)n * 256 + c) * 8192 + t0 + t];
    }
    __syncthreads();

    // GEMM l0: M=128 (wave w -> mtile w), K=256
    f32x4 z = {0.f,0.f,0.f,0.f};
    f32x4 acc[4] = {z, z, z, z};
    #pragma unroll
    for (int kb = 0; kb < 8; ++kb) {
        int koff = kb * 32 + q * 8;
        bf16x8 bf[4];
        #pragma unroll
        for (int nt = 0; nt < 4; ++nt)
            bf[nt] = *(const bf16x8*)(xt + (nt * 16 + i16) * PX + koff);
        bf16x8 af = *(const bf16x8*)(A1 + (((size_t)w * 8 + kb) * 64 + lane) * 8);
        #pragma unroll
        for (int nt = 0; nt < 4; ++nt) acc[nt] = mfma16(af, bf[nt], acc[nt]);
    }
    #pragma unroll
    for (int nt = 0; nt < 4; ++nt)
        #pragma unroll
        for (int j = 0; j < 4; ++j)
            l0[(nt * 16 + i16) * PL + w * 16 + q * 4 + j] = (bf16_t)acc[nt][j];
    __syncthreads();

    {   // copy l0 -> global [N][L][128]
        int r = tid >> 4, col = (tid & 15) * 8;
        #pragma unroll
        for (int p = 0; p < 2; ++p) {
            int rr = r + p * 32;
            *(i32x4*)(l_out + ((size_t)n * 8192 + t0 + rr) * 128 + col) =
                *(const i32x4*)(l0 + rr * PL + col);
        }
    }

    if (t0 >= 4096) {  // s0: M=256, K=128
        f32x4 a2[2][4] = {{z,z,z,z},{z,z,z,z}};
        #pragma unroll
        for (int kb = 0; kb < 4; ++kb) {
            int koff = kb * 32 + q * 8;
            bf16x8 bf[4];
            #pragma unroll
            for (int nt = 0; nt < 4; ++nt)
                bf[nt] = *(const bf16x8*)(l0 + (nt * 16 + i16) * PL + koff);
            #pragma unroll
            for (int mt2 = 0; mt2 < 2; ++mt2) {
                bf16x8 af = *(const bf16x8*)(A2 + ((((size_t)2 * w + mt2) * 4 + kb) * 64 + lane) * 8);
                #pragma unroll
                for (int nt = 0; nt < 4; ++nt) a2[mt2][nt] = mfma16(af, bf[nt], a2[mt2][nt]);
            }
        }
        float* sp = s + (size_t)n * 256 * 4096 + (t0 - 4096);
        #pragma unroll
        for (int mt2 = 0; mt2 < 2; ++mt2)
            #pragma unroll
            for (int nt = 0; nt < 4; ++nt)
                #pragma unroll
                for (int j = 0; j < 4; ++j) {
                    int o = (2 * w + mt2) * 16 + q * 4 + j;
                    sp[(size_t)o * 4096 + nt * 16 + i16] = a2[mt2][nt][j];
                }
    }
}

// ---------------- fused WaveNet layer ----------------
// Wave w: GEMM1 mtiles (w = sigmoid ch 16w.., w+8 = matching tanh ch), all 4
// ntiles -> gate in-register, weights read once per block.  GEMM2: res mtile w;
// GEMM3: skip mtiles 2w,2w+1.
__global__ __launch_bounds__(512, 4) void layer_kernel(
    const bf16_t* __restrict__ l_in, bf16_t* __restrict__ l_out,
    float* __restrict__ s,
    const bf16_t* __restrict__ Ad, const bf16_t* __restrict__ Ar,
    const bf16_t* __restrict__ Ak, const float* __restrict__ cond,
    int dil, int t_base, int do_res) {
    __shared__ __align__(16) bf16_t l_cur[TT * PL];
    __shared__ __align__(16) bf16_t l_del[TT * PL];   // reused for bf16 sum after GEMM1
    __shared__ __align__(16) bf16_t g_lds[TT * PL];

    int tid = threadIdx.x;
    int n = blockIdx.y, t0 = t_base + blockIdx.x * TT;
    int lane = tid & 63, w = tid >> 6, i16 = lane & 15, q = lane >> 4;

    {   // stage l_cur, l_del (delayed by dil, zero-pad)
        int r = tid >> 4, col = (tid & 15) * 8;
        size_t base = (size_t)n * 8192;
        #pragma unroll
        for (int p = 0; p < 2; ++p) {
            int rr = r + p * 32;
            *(i32x4*)(l_cur + rr * PL + col) =
                *(const i32x4*)(l_in + (base + t0 + rr) * 128 + col);
            int gp = t0 - dil + rr;
            i32x4 v = {0, 0, 0, 0};
            if (gp >= 0) v = *(const i32x4*)(l_in + (base + gp) * 128 + col);
            *(i32x4*)(l_del + rr * PL + col) = v;
        }
    }
    __syncthreads();

    // GEMM1: d = [W0 W1] @ [l_del; l_cur], M=256 K=256.
    f32x4 z = {0.f,0.f,0.f,0.f};
    f32x4 accs[4] = {z,z,z,z}, acct[4] = {z,z,z,z};
    const bf16x8* AdF = (const bf16x8*)Ad;
    #pragma unroll
    for (int kb = 0; kb < 8; ++kb) {
        const bf16_t* bsrc = (kb < 4) ? l_del : l_cur;
        int koff = (kb & 3) * 32 + q * 8;
        bf16x8 bf[4];
        #pragma unroll
        for (int nt = 0; nt < 4; ++nt)
            bf[nt] = *(const bf16x8*)(bsrc + (nt * 16 + i16) * PL + koff);
        bf16x8 a_s = AdF[((size_t)w * 8 + kb) * 64 + lane];
        bf16x8 a_t = AdF[((size_t)(w + 8) * 8 + kb) * 64 + lane];
        #pragma unroll
        for (int nt = 0; nt < 4; ++nt) {
            accs[nt] = mfma16(a_s, bf[nt], accs[nt]);
            acct[nt] = mfma16(a_t, bf[nt], acct[nt]);
        }
    }

    // gate fully in-register: g[c] = sigmoid(d[c]+cv) * tanh(d[c+128]+cv')
    {
        const float* cn = cond + (size_t)n * 4096;
        int c_base = w * 16 + q * 4;
        float cv_s[4], cv_t[4];
        #pragma unroll
        for (int j = 0; j < 4; ++j) {
            cv_s[j] = cn[(c_base + j) * 16 + i16];
            cv_t[j] = cn[(c_base + j + 128) * 16 + i16];
        }
        #pragma unroll
        for (int nt = 0; nt < 4; ++nt) {
            bf16x4 g4;
            #pragma unroll
            for (int j = 0; j < 4; ++j) {
                float vlo = accs[nt][j] + cv_s[j];
                float vhi = acct[nt][j] + cv_t[j];
                float sg = 1.0f / (1.0f + __expf(-vlo));
                float th = 1.0f - 2.0f / (1.0f + __expf(2.0f * vhi));
                g4[j] = (bf16_t)(sg * th);
            }
            *(bf16x4*)(g_lds + (nt * 16 + i16) * PL + c_base) = g4;
        }
    }
    __syncthreads();   // g_lds ready; l_del reads done

    // GEMM2 (res mtile w) + GEMM3 (skip mtiles 2w,2w+1), shared B frags, K=128
    int do_skip = (t0 >= 4096);
    f32x4 acc2[4] = {z,z,z,z};
    f32x4 acc3[2][4] = {{z,z,z,z},{z,z,z,z}};
    const bf16x8* ArF = (const bf16x8*)Ar;
    const bf16x8* AkF = (const bf16x8*)Ak;
    #pragma unroll
    for (int kb = 0; kb < 4; ++kb) {
        int koff = kb * 32 + q * 8;
        bf16x8 bf[4];
        #pragma unroll
        for (int nt = 0; nt < 4; ++nt)
            bf[nt] = *(const bf16x8*)(g_lds + (nt * 16 + i16) * PL + koff);
        if (do_res) {
            bf16x8 ar = ArF[((size_t)w * 4 + kb) * 64 + lane];
            #pragma unroll
            for (int nt = 0; nt < 4; ++nt) acc2[nt] = mfma16(ar, bf[nt], acc2[nt]);
        }
        if (do_skip) {
            #pragma unroll
            for (int mt2 = 0; mt2 < 2; ++mt2) {
                bf16x8 ak = AkF[((size_t)(2 * w + mt2) * 4 + kb) * 64 + lane];
                #pragma unroll
                for (int nt = 0; nt < 4; ++nt)
                    acc3[mt2][nt] = mfma16(ak, bf[nt], acc3[mt2][nt]);
            }
        }
    }

    if (do_skip) {   // accumulate into s (only t >= 4096 contributes to output)
        float* sp = s + (size_t)n * 256 * 4096 + (t0 - 4096);
        #pragma unroll
        for (int mt2 = 0; mt2 < 2; ++mt2)
            #pragma unroll
            for (int nt = 0; nt < 4; ++nt)
                #pragma unroll
                for (int j = 0; j < 4; ++j) {
                    int o = (2 * w + mt2) * 16 + q * 4 + j;
                    sp[(size_t)o * 4096 + nt * 16 + i16] += acc3[mt2][nt][j];
                }
    }

    if (do_res) {
        // sum = f32(l_cur) + res, single rounding to bf16, into l_del [t][PL]
        int c_base = w * 16 + q * 4;
        #pragma unroll
        for (int nt = 0; nt < 4; ++nt) {
            int trow = (nt * 16 + i16) * PL;
            bf16x4 lv = *(const bf16x4*)(l_cur + trow + c_base);
            bf16x4 o4;
            #pragma unroll
            for (int j = 0; j < 4; ++j)
                o4[j] = (bf16_t)((float)lv[j] + acc2[nt][j]);
            *(bf16x4*)(l_del + trow + c_base) = o4;
        }
        __syncthreads();
        // coalesced copy l_del -> l_out
        int t = tid >> 3, c0 = (tid & 7) * 16;
        bf16_t* dst = l_out + ((size_t)n * 8192 + t0 + t) * 128 + c0;
        *(i32x4*)dst = *(const i32x4*)(l_del + t * PL + c0);
        *(i32x4*)(dst + 8) = *(const i32x4*)(l_del + t * PL + c0 + 8);
    }
}

// ---------------- end: out = relu(end1@relu(s) + b1 + cond2_tiled) ----------------
__global__ __launch_bounds__(512) void end_kernel(
    const float* __restrict__ s, float* __restrict__ out,
    const bf16_t* __restrict__ Ae, const float* __restrict__ cond2,
    const float* __restrict__ b1) {
    __shared__ __align__(16) bf16_t st[TT * PX];
    __shared__ float c2[4096];
    __shared__ float b1s[256];
    int tid = threadIdx.x;
    int n = blockIdx.y, t0 = blockIdx.x * TT;
    int lane = tid & 63, w = tid >> 6, i16 = lane & 15, q = lane >> 4;

    {
        int t = tid & 63;
        for (int c = tid >> 6; c < 256; c += 8) {
            float v = s[((size_t)n * 256 + c) * 4096 + t0 + t];
            st[t * PX + c] = (bf16_t)fmaxf(v, 0.f);
        }
        const f32x4* cc = (const f32x4*)(cond2 + (size_t)n * 4096);
        for (int idx = tid; idx < 1024; idx += 512) ((f32x4*)c2)[idx] = cc[idx];
        if (tid < 64) ((f32x4*)b1s)[tid] = ((const f32x4*)b1)[tid];
    }
    __syncthreads();

    f32x4 z = {0.f,0.f,0.f,0.f};
    f32x4 acc[2][4] = {{z,z,z,z},{z,z,z,z}};
    #pragma unroll
    for (int kb = 0; kb < 8; ++kb) {
        int koff = kb * 32 + q * 8;
        bf16x8 bf[4];
        #pragma unroll
        for (int nt = 0; nt < 4; ++nt)
            bf[nt] = *(const bf16x8*)(st + (nt * 16 + i16) * PX + koff);
        #pragma unroll
        for (int mt2 = 0; mt2 < 2; ++mt2) {
            bf16x8 af = *(const bf16x8*)(Ae + ((((size_t)2 * w + mt2) * 8 + kb) * 64 + lane) * 8);
            #pragma unroll
            for (int nt = 0; nt < 4; ++nt) acc[mt2][nt] = mfma16(af, bf[nt], acc[mt2][nt]);
        }
    }
    #pragma unroll
    for (int mt2 = 0; mt2 < 2; ++mt2)
        #pragma unroll
        for (int j = 0; j < 4; ++j) {
            int o = (2 * w + mt2) * 16 + q * 4 + j;
            float bb = b1s[o] + c2[o * 16 + i16];
            #pragma unroll
            for (int nt = 0; nt < 4; ++nt) {
                float v = acc[mt2][nt][j] + bb;
                out[((size_t)n * 256 + o) * 4096 + t0 + nt * 16 + i16] = fmaxf(v, 0.f);
            }
        }
}

extern "C" void kernel_launch(void* const* d_in, const int* in_sizes, int n_in,
                              void* d_out, int out_size, void* d_ws, size_t ws_size,
                              hipStream_t stream) {
    const float* x   = (const float*)d_in[0];
    const float* en  = (const float*)d_in[1];
    const float* s1w = (const float*)d_in[2];
    const float* s2w = (const float*)d_in[3];
    const float* cw  = (const float*)d_in[4];
    const float* dw  = (const float*)d_in[5];
    const float* rw  = (const float*)d_in[6];
    const float* kw  = (const float*)d_in[7];
    const float* e1w = (const float*)d_in[8];
    const float* e1b = (const float*)d_in[9];
    const float* e2w = (const float*)d_in[10];
    const float* e2b = (const float*)d_in[11];
    float* out = (float*)d_out;

    char* p = (char*)d_ws;
    auto take = [&](size_t bytes) {
        char* r = p;
        p += (bytes + 255) & ~(size_t)255;
        return r;
    };
    bf16_t* A1   = (bf16_t*)take((size_t)128 * 256 * 2);
    bf16_t* A2   = (bf16_t*)take((size_t)256 * 128 * 2);
    bf16_t* Ae   = (bf16_t*)take((size_t)256 * 256 * 2);
    bf16_t* Adil = (bf16_t*)take((size_t)30 * 65536 * 2);
    bf16_t* Ares = (bf16_t*)take((size_t)30 * 16384 * 2);
    bf16_t* Askp = (bf16_t*)take((size_t)30 * 32768 * 2);
    float*  condA= (float*)take((size_t)30 * 16384 * 4);
    float*  cond2= (float*)take((size_t)16384 * 4);
    bf16_t* la   = (bf16_t*)take((size_t)4 * 8192 * 128 * 2);
    bf16_t* lb   = (bf16_t*)take((size_t)4 * 8192 * 128 * 2);
    float*  sbuf = (float*)take((size_t)4 * 256 * 4096 * 4);

    conv_batch<<<30 * 16384 / 256, 256, 0, stream>>>(rw, Ares, 128, 128, 30);
    conv_batch<<<30 * 32768 / 256, 256, 0, stream>>>(kw, Askp, 256, 128, 30);
    conv_batch<<<128 * 256 / 256, 256, 0, stream>>>(s1w, A1, 128, 256, 1);
    conv_batch<<<256 * 128 / 256, 256, 0, stream>>>(s2w, A2, 256, 128, 1);
    conv_batch<<<256 * 256 / 256, 256, 0, stream>>>(e1w, Ae, 256, 256, 1);
    conv_dil<<<30 * 65536 / 256, 256, 0, stream>>>(dw, Adil);
    cond_kernel<<<124, 256, 0, stream>>>(cw, e2w, e2b, en, condA, cond2);

    // causal trim: a[i] = first (tile-aligned) position layer i must compute
    int a[30];
    a[29] = 4096;
    for (int i = 28; i >= 0; --i) {
        int nx = a[i + 1] - (1 << ((i + 1) % 10));
        a[i] = nx < 4096 ? (nx & ~63) : 4096;
    }

    start_kernel<<<dim3(127, 4), 512, 0, stream>>>(x, la, sbuf, A1, A2);
    bf16_t* src = la;
    bf16_t* dst = lb;
    for (int i = 0; i < 30; ++i) {
        int ntiles = (8192 - a[i]) / 64;
        layer_kernel<<<dim3(ntiles, 4), 512, 0, stream>>>(src, dst, sbuf,
            Adil + (size_t)i * 65536, Ares + (size_t)i * 16384,
            Askp + (size_t)i * 32768, condA + (size_t)i * 16384,
            1 << (i % 10), a[i], i < 29 ? 1 : 0);
        bf16_t* t = src; src = dst; dst = t;
    }
    end_kernel<<<dim3(64, 4), 512, 0, stream>>>(sbuf, out, Ae, cond2, e1b);
}